// Round 6
// baseline (71.170 us; speedup 1.0000x reference)
//
#include <hip/hip_runtime.h>

// Block-mask metadata for flex-attention style sparsity — single fused kernel.
// M = N = 32768 tokens, QB = KB = 128 -> 256 x 256 block mask.
//
// bm[qb][kb] = any(q <= kv && doc[q]==doc[kv]) over the 128x128 tile
//            = 0                        if kb < qb
//            = 1                        if kb == qb  (q==kv pair on diagonal)
//            = docs(qb) ∩ docs(kb) != 0 if kb > qb   (causal always true)
//
// Workgroup r computes row r (kv side) and column r (q side) of the block
// mask. Block summaries (min/max/uniform/first) are recomputed per-WG with a
// COALESCED wave-cooperative pass: iter i, thread t loads int4 #(i*256+t)
// (contiguous 4 KB per iter), 5-step __shfl_xor reduce within aligned
// 32-lane groups -> one block summary per group. 4x fewer cacheline
// requests than the previous per-thread strided version.
//
// Outputs (flat int32, reference return order):
//   [0,256)        kv_num_blocks
//   [256,65792)    kv_indices      per-row stable-desc argsort of {0,1}
//   [65792,66048)  q_num_blocks
//   [66048,131584) q_indices       per-col stable-desc argsort (transposed)
//   [131584..5]    kv_block_size=128, q_block_size=128

#define NBLK 256   // blocks per side
#define TOK  128   // tokens per block

// bm value for tile (qb, kb); O(1) fast paths; generic fallback never taken
// for the fixed setup_inputs (every 128-block is doc-uniform).
__device__ __forceinline__ int bm_val(int qb, int kb, const int4* S,
                                      const int* __restrict__ doc) {
    if (kb < qb) return 0;
    if (kb == qb) return 1;
    int4 a = S[qb], b = S[kb];
    if (a.y < b.x || b.y < a.x) return 0;          // doc ranges disjoint
    if (a.z && b.z) return (a.w == b.w) ? 1 : 0;   // both uniform
    for (int i = 0; i < TOK; ++i) {                // generic fallback
        int dq = doc[qb * TOK + i];
        for (int j = 0; j < TOK; ++j)
            if (dq == doc[kb * TOK + j]) return 1;
    }
    return 0;
}

__global__ __launch_bounds__(256) void fused_mask_kernel(
        const int* __restrict__ doc, int* __restrict__ out) {
    const int r = blockIdx.x;      // 0..255: row r AND column r
    const int t = threadIdx.x;     // 0..255

    __shared__ int4 S[NBLK];
    __shared__ int wsum[4];

    // ---- coalesced per-block summary ----
    // int4 index g = i*256 + t covers tokens [4g, 4g+4) -> block g>>5.
    // 32 consecutive threads (aligned 32-lane group) cover one block.
    {
        const int4* dv = (const int4*)doc;
#pragma unroll
        for (int i = 0; i < 32; ++i) {
            const int g = i * 256 + t;
            int4 v = dv[g];                         // coalesced 4 KB / iter
            int mn = min(min(v.x, v.y), min(v.z, v.w));
            int mx = max(max(v.x, v.y), max(v.z, v.w));
            int first = v.x;                        // valid at group leader
#pragma unroll
            for (int o = 1; o <= 16; o <<= 1) {     // within 32-lane group
                mn = min(mn, __shfl_xor(mn, o, 32));
                mx = max(mx, __shfl_xor(mx, o, 32));
            }
            if ((t & 31) == 0)
                S[g >> 5] = make_int4(mn, mx, (mn == mx) ? 1 : 0, first);
        }
    }
    __syncthreads();

    int* kvn = out;                       // 256
    int* kvi = out + 256;                 // 65536
    int* qn  = out + 256 + 65536;         // 256
    int* qi  = out + 512 + 65536;         // 65536

    const int lane = t & 63;
    const int wv   = t >> 6;

    // ---------- row r: kv_num_blocks / kv_indices ----------
    {
        int v = bm_val(r, t, S, doc);
        unsigned long long m = __ballot(v != 0);
        int prew = __popcll(m & ((1ULL << lane) - 1ULL));
        int wtot = __popcll(m);
        if (lane == 0) wsum[wv] = wtot;
        __syncthreads();
        int base = 0;
        for (int i = 0; i < wv; ++i) base += wsum[i];
        int total = wsum[0] + wsum[1] + wsum[2] + wsum[3];
        int pre = base + prew;                       // ones strictly before t
        int rank = v ? pre : (total + (t - pre));    // stable desc argsort rank
        kvi[r * NBLK + rank] = t;
        if (t == 0) kvn[r] = total;
        __syncthreads();   // wsum reused below
    }

    // ---------- column r: q_num_blocks / q_indices ----------
    {
        int v = bm_val(t, r, S, doc);
        unsigned long long m = __ballot(v != 0);
        int prew = __popcll(m & ((1ULL << lane) - 1ULL));
        int wtot = __popcll(m);
        if (lane == 0) wsum[wv] = wtot;
        __syncthreads();
        int base = 0;
        for (int i = 0; i < wv; ++i) base += wsum[i];
        int total = wsum[0] + wsum[1] + wsum[2] + wsum[3];
        int pre = base + prew;
        int rank = v ? pre : (total + (t - pre));
        qi[r * NBLK + rank] = t;
        if (t == 0) qn[r] = total;
    }

    if (r == 0 && t == 0) {
        out[512 + 2 * 65536 + 0] = 128;   // kv_block_size
        out[512 + 2 * 65536 + 1] = 128;   // q_block_size
    }
}

extern "C" void kernel_launch(void* const* d_in, const int* in_sizes, int n_in,
                              void* d_out, int out_size, void* d_ws, size_t ws_size,
                              hipStream_t stream) {
    // d_in[0] = x (8x128 f32, unused), d_in[1] = document_id (int32[32768])
    const int* doc = (const int*)d_in[1];
    int* out = (int*)d_out;

    hipLaunchKernelGGL(fused_mask_kernel, dim3(NBLK), dim3(256), 0, stream,
                       doc, out);
}

// Round 7
// 58.647 us; speedup vs baseline: 1.2135x; 1.2135x over previous
//
#include <hip/hip_runtime.h>

// Block-mask metadata for flex-attention style sparsity — single fused kernel.
// M = N = 32768 tokens, QB = KB = 128 -> 256 x 256 block mask.
//
// bm[qb][kb] = any(q <= kv && doc[q]==doc[kv]) over the 128x128 tile
//            = 0                        if kb < qb
//            = 1                        if kb == qb  (q==kv pair on diagonal)
//            = docs(qb) ∩ docs(kb) != 0 if kb > qb   (causal always true)
//
// Key cost insight (R4/R6 post-mortems): the per-WG block-summary recompute
// was the entire controllable cost (strided scan ~10us, shfl-reduce ~20us at
// 4 waves/CU). For the fixed input, doc boundaries are 128-aligned -> every
// block is doc-uniform, so the summary is just {first, last} (2 loads/thread).
// A per-thread full-scan fallback (taken only iff first != last) keeps
// generic correctness at zero cost on the real input.
//
// Outputs (flat int32, reference return order):
//   [0,256)        kv_num_blocks
//   [256,65792)    kv_indices      per-row stable-desc argsort of {0,1}
//   [65792,66048)  q_num_blocks
//   [66048,131584) q_indices       per-col stable-desc argsort (transposed)
//   [131584..5]    kv_block_size=128, q_block_size=128

#define NBLK 256   // blocks per side
#define TOK  128   // tokens per block

// bm value for tile (qb, kb); O(1) fast paths; pairwise fallback only for
// non-uniform blocks with overlapping ranges (never taken on real input).
__device__ __forceinline__ int bm_val(int qb, int kb, const int4* S,
                                      const int* __restrict__ doc) {
    if (kb < qb) return 0;
    if (kb == qb) return 1;
    int4 a = S[qb], b = S[kb];
    if (a.y < b.x || b.y < a.x) return 0;          // doc ranges disjoint
    if (a.z && b.z) return (a.w == b.w) ? 1 : 0;   // both uniform
    for (int i = 0; i < TOK; ++i) {                // generic fallback
        int dq = doc[qb * TOK + i];
        for (int j = 0; j < TOK; ++j)
            if (dq == doc[kb * TOK + j]) return 1;
    }
    return 0;
}

__global__ __launch_bounds__(256) void fused_mask_kernel(
        const int* __restrict__ doc, int* __restrict__ out) {
    const int r = blockIdx.x;      // 0..255: row r AND column r
    const int t = threadIdx.x;     // 0..255

    __shared__ int4 S[NBLK];
    __shared__ int wsum[4];

    // ---- per-block summary: 2 loads/thread, fallback scan iff non-uniform --
    {
        int first = doc[t * TOK];
        int last  = doc[t * TOK + TOK - 1];
        int mn, mx, uni;
        if (first == last) {                 // uniform block (always, here)
            mn = mx = first; uni = 1;
        } else {                             // rare: true min/max via scan
            const int4* p = (const int4*)(doc + t * TOK);
            mn = first; mx = first;
            for (int i = 0; i < TOK / 4; ++i) {
                int4 v = p[i];
                mn = min(mn, min(min(v.x, v.y), min(v.z, v.w)));
                mx = max(mx, max(max(v.x, v.y), max(v.z, v.w)));
            }
            uni = 0;
        }
        S[t] = make_int4(mn, mx, uni, first);
    }
    __syncthreads();

    int* kvn = out;                       // 256
    int* kvi = out + 256;                 // 65536
    int* qn  = out + 256 + 65536;         // 256
    int* qi  = out + 512 + 65536;         // 65536

    const int lane = t & 63;
    const int wv   = t >> 6;

    // ---------- row r: kv_num_blocks / kv_indices ----------
    {
        int v = bm_val(r, t, S, doc);
        unsigned long long m = __ballot(v != 0);
        int prew = __popcll(m & ((1ULL << lane) - 1ULL));
        int wtot = __popcll(m);
        if (lane == 0) wsum[wv] = wtot;
        __syncthreads();
        int base = 0;
        for (int i = 0; i < wv; ++i) base += wsum[i];
        int total = wsum[0] + wsum[1] + wsum[2] + wsum[3];
        int pre = base + prew;                       // ones strictly before t
        int rank = v ? pre : (total + (t - pre));    // stable desc argsort rank
        kvi[r * NBLK + rank] = t;
        if (t == 0) kvn[r] = total;
        __syncthreads();   // wsum reused below
    }

    // ---------- column r: q_num_blocks / q_indices ----------
    {
        int v = bm_val(t, r, S, doc);
        unsigned long long m = __ballot(v != 0);
        int prew = __popcll(m & ((1ULL << lane) - 1ULL));
        int wtot = __popcll(m);
        if (lane == 0) wsum[wv] = wtot;
        __syncthreads();
        int base = 0;
        for (int i = 0; i < wv; ++i) base += wsum[i];
        int total = wsum[0] + wsum[1] + wsum[2] + wsum[3];
        int pre = base + prew;
        int rank = v ? pre : (total + (t - pre));
        qi[r * NBLK + rank] = t;
        if (t == 0) qn[r] = total;
    }

    if (r == 0 && t == 0) {
        out[512 + 2 * 65536 + 0] = 128;   // kv_block_size
        out[512 + 2 * 65536 + 1] = 128;   // q_block_size
    }
}

extern "C" void kernel_launch(void* const* d_in, const int* in_sizes, int n_in,
                              void* d_out, int out_size, void* d_ws, size_t ws_size,
                              hipStream_t stream) {
    // d_in[0] = x (8x128 f32, unused), d_in[1] = document_id (int32[32768])
    const int* doc = (const int*)d_in[1];
    int* out = (int*)d_out;

    hipLaunchKernelGGL(fused_mask_kernel, dim3(NBLK), dim3(256), 0, stream,
                       doc, out);
}

// Round 8
// 58.610 us; speedup vs baseline: 1.2143x; 1.0006x over previous
//
#include <hip/hip_runtime.h>

// Block-mask metadata for flex-attention sparsity — one WAVE per row/col pair,
// zero barriers, zero LDS.  M = N = 32768, QB = KB = 128 -> 256x256 blocks.
//
// bm[qb][kb] = 0 if kb<qb; 1 if kb==qb; else docs(qb) ∩ docs(kb) != ∅.
// Stable-descending argsort of a 0/1 row == indices of ones then zeros, both
// in ascending order -> pure ballot/popcount rank computation.
//
// Each 64-lane WG r: lane l owns block-columns {l, 64+l, 128+l, 192+l}
// (4 "slots", all compile-time indexed -> stays in registers). Block summary
// = {min,max,uniform,first}; fast path reads only doc[b*128] and
// doc[b*128+127] (every 128-block is doc-uniform for this input; generic
// scan fallback kept for non-uniform blocks). Summary of block r is pulled
// from its owning lane via cndmask-select + __shfl.
//
// Outputs (flat int32, reference return order):
//   [0,256)        kv_num_blocks
//   [256,65792)    kv_indices
//   [65792,66048)  q_num_blocks
//   [66048,131584) q_indices
//   [131584..5]    kv_block_size=128, q_block_size=128

#define NBLK 256
#define TOK  128

// Generic pairwise fallback — only for non-uniform overlapping blocks
// (never taken for the fixed setup_inputs).
__device__ __noinline__ int bm_fallback(int qb, int kb,
                                        const int* __restrict__ doc) {
    for (int i = 0; i < TOK; ++i) {
        int dq = doc[qb * TOK + i];
        for (int j = 0; j < TOK; ++j)
            if (dq == doc[kb * TOK + j]) return 1;
    }
    return 0;
}

__device__ __forceinline__ int bm_u(int qb, int kb,
                                    int qmn, int qmx, int qun, int qf,
                                    int kmn, int kmx, int kun, int kf,
                                    const int* __restrict__ doc) {
    if (kb < qb) return 0;
    if (kb == qb) return 1;
    if (qmx < kmn || kmx < qmn) return 0;        // ranges disjoint
    if (qun && kun) return (qf == kf) ? 1 : 0;   // both uniform
    return bm_fallback(qb, kb, doc);
}

// Per-slot block summary: 2 loads fast path, scan fallback if first!=last.
#define SUMM(B, MN, MX, UN, FS)                                              \
    {                                                                        \
        const int b_ = (B);                                                  \
        int first_ = doc[b_ * TOK];                                          \
        int last_  = doc[b_ * TOK + TOK - 1];                                \
        if (first_ == last_) { MN = MX = first_; UN = 1; }                   \
        else {                                                               \
            const int4* p_ = (const int4*)(doc + b_ * TOK);                  \
            int mn_ = first_, mx_ = first_;                                  \
            for (int i_ = 0; i_ < TOK / 4; ++i_) {                           \
                int4 v_ = p_[i_];                                            \
                mn_ = min(mn_, min(min(v_.x, v_.y), min(v_.z, v_.w)));       \
                mx_ = max(mx_, max(max(v_.x, v_.y), max(v_.z, v_.w)));       \
            }                                                                \
            MN = mn_; MX = mx_; UN = 0;                                      \
        }                                                                    \
        FS = first_;                                                         \
    }

__global__ __launch_bounds__(64) void fused_mask_kernel(
        const int* __restrict__ doc, int* __restrict__ out) {
    const int r = blockIdx.x;      // row r AND column r
    const int l = threadIdx.x;     // lane 0..63

    // ---- summaries for the 4 blocks this lane owns ----
    int mn0, mx0, un0, f0;  SUMM(l,       mn0, mx0, un0, f0);
    int mn1, mx1, un1, f1;  SUMM(64 + l,  mn1, mx1, un1, f1);
    int mn2, mx2, un2, f2;  SUMM(128 + l, mn2, mx2, un2, f2);
    int mn3, mx3, un3, f3;  SUMM(192 + l, mn3, mx3, un3, f3);

    // ---- summary of block r: owning lane = r&63, slot = r>>6 ----
    const int rs = r >> 6, rl = r & 63;
    int mnr = rs == 0 ? mn0 : rs == 1 ? mn1 : rs == 2 ? mn2 : mn3;
    int mxr = rs == 0 ? mx0 : rs == 1 ? mx1 : rs == 2 ? mx2 : mx3;
    int unr = rs == 0 ? un0 : rs == 1 ? un1 : rs == 2 ? un2 : un3;
    int fr  = rs == 0 ? f0  : rs == 1 ? f1  : rs == 2 ? f2  : f3;
    mnr = __shfl(mnr, rl);
    mxr = __shfl(mxr, rl);
    unr = __shfl(unr, rl);
    fr  = __shfl(fr,  rl);

    int* kvn = out;                       // 256
    int* kvi = out + 256;                 // 65536
    int* qn  = out + 256 + 65536;         // 256
    int* qi  = out + 512 + 65536;         // 65536

    const unsigned long long below = (1ULL << l) - 1ULL;   // l<64, safe
    const int c0 = l, c1 = 64 + l, c2 = 128 + l, c3 = 192 + l;

    // ---------- row r: bm(r, c) ----------
    {
        int v0 = bm_u(r, c0, mnr, mxr, unr, fr, mn0, mx0, un0, f0, doc);
        int v1 = bm_u(r, c1, mnr, mxr, unr, fr, mn1, mx1, un1, f1, doc);
        int v2 = bm_u(r, c2, mnr, mxr, unr, fr, mn2, mx2, un2, f2, doc);
        int v3 = bm_u(r, c3, mnr, mxr, unr, fr, mn3, mx3, un3, f3, doc);
        unsigned long long m0 = __ballot(v0 != 0), m1 = __ballot(v1 != 0);
        unsigned long long m2 = __ballot(v2 != 0), m3 = __ballot(v3 != 0);
        int t0 = __popcll(m0), t1 = __popcll(m1), t2 = __popcll(m2);
        int total = t0 + t1 + t2 + __popcll(m3);
        int p0 = __popcll(m0 & below);
        int p1 = t0 + __popcll(m1 & below);
        int p2 = t0 + t1 + __popcll(m2 & below);
        int p3 = t0 + t1 + t2 + __popcll(m3 & below);
        kvi[r * NBLK + (v0 ? p0 : total + (c0 - p0))] = c0;
        kvi[r * NBLK + (v1 ? p1 : total + (c1 - p1))] = c1;
        kvi[r * NBLK + (v2 ? p2 : total + (c2 - p2))] = c2;
        kvi[r * NBLK + (v3 ? p3 : total + (c3 - p3))] = c3;
        if (l == 0) kvn[r] = total;
    }

    // ---------- column r: bm(q, r) ----------
    {
        int v0 = bm_u(c0, r, mn0, mx0, un0, f0, mnr, mxr, unr, fr, doc);
        int v1 = bm_u(c1, r, mn1, mx1, un1, f1, mnr, mxr, unr, fr, doc);
        int v2 = bm_u(c2, r, mn2, mx2, un2, f2, mnr, mxr, unr, fr, doc);
        int v3 = bm_u(c3, r, mn3, mx3, un3, f3, mnr, mxr, unr, fr, doc);
        unsigned long long m0 = __ballot(v0 != 0), m1 = __ballot(v1 != 0);
        unsigned long long m2 = __ballot(v2 != 0), m3 = __ballot(v3 != 0);
        int t0 = __popcll(m0), t1 = __popcll(m1), t2 = __popcll(m2);
        int total = t0 + t1 + t2 + __popcll(m3);
        int p0 = __popcll(m0 & below);
        int p1 = t0 + __popcll(m1 & below);
        int p2 = t0 + t1 + __popcll(m2 & below);
        int p3 = t0 + t1 + t2 + __popcll(m3 & below);
        qi[r * NBLK + (v0 ? p0 : total + (c0 - p0))] = c0;
        qi[r * NBLK + (v1 ? p1 : total + (c1 - p1))] = c1;
        qi[r * NBLK + (v2 ? p2 : total + (c2 - p2))] = c2;
        qi[r * NBLK + (v3 ? p3 : total + (c3 - p3))] = c3;
        if (l == 0) qn[r] = total;
    }

    if (r == 0 && l == 0) {
        out[512 + 2 * 65536 + 0] = 128;   // kv_block_size
        out[512 + 2 * 65536 + 1] = 128;   // q_block_size
    }
}

extern "C" void kernel_launch(void* const* d_in, const int* in_sizes, int n_in,
                              void* d_out, int out_size, void* d_ws, size_t ws_size,
                              hipStream_t stream) {
    // d_in[0] = x (8x128 f32, unused), d_in[1] = document_id (int32[32768])
    const int* doc = (const int*)d_in[1];
    int* out = (int*)d_out;

    hipLaunchKernelGGL(fused_mask_kernel, dim3(NBLK), dim3(64), 0, stream,
                       doc, out);
}